// Round 1
// baseline (280.643 us; speedup 1.0000x reference)
//
#include <hip/hip_runtime.h>
#include <hip/hip_bf16.h>
#include <stdint.h>

using bf16 = __hip_bfloat16;
typedef __bf16 bf16x8 __attribute__((ext_vector_type(8)));
typedef float  f32x4  __attribute__((ext_vector_type(4)));

#define AS1 __attribute__((address_space(1)))
#define AS3 __attribute__((address_space(3)))

__device__ __forceinline__ void async_cp16(const void* g, void* l) {
    __builtin_amdgcn_global_load_lds((const AS1 void*)g, (AS3 void*)l, 16, 0, 0);
}

enum { F_CSKIP = 1, F_CK = 2, F_OBF16 = 4, F_BIAS_N = 8, F_BIAS_M = 16 };

// C[M,N] = scale * A[M,K] * B[N,K]^T (+ bias).  Both operands K-major bf16.
// 128x128 tile per 256-thread block, BK=64, 16x16x32 bf16 MFMA, XOR-swizzled LDS.
__global__ __launch_bounds__(256, 2) void gemm_bt(
    const bf16* __restrict__ A, const bf16* __restrict__ B, void* __restrict__ Cv,
    long lda, long ldb, long ldc,
    long strideA, long strideB, long strideC,
    int K, int flags, const float* __restrict__ bias, float scale)
{
    const int bm = blockIdx.y, bn = blockIdx.x, bz = blockIdx.z;
    if ((flags & F_CSKIP) && bn > bm) return;           // causal upper blocks
    const int Keff = (flags & F_CK) ? (bm + 1) * 128 : K;  // causal K-limit

    __shared__ bf16 sA[128 * 64];
    __shared__ bf16 sB[128 * 64];

    const int tid  = threadIdx.x;
    const int wave = tid >> 6, lane = tid & 63;
    const int wm = (wave >> 1) * 64, wn = (wave & 1) * 64;
    const int quad = lane >> 4, r16 = lane & 15;

    const bf16* Ab = A + (long)bz * strideA + (long)bm * 128 * lda;
    const bf16* Bb = B + (long)bz * strideB + (long)bn * 128 * ldb;

    // staging: each wave stages 32 rows of A and 32 rows of B (4 chunks of 8 rows, 1KB each)
    // LDS layout: row-major [128][64] bf16, 16B blocks XOR-swizzled: block c of row r at slot c^(r&7)
    const int rl = lane >> 3;              // row within 8-row chunk
    const int cb = (lane & 7) ^ rl;        // which global 16B block this lane fetches
    const bf16* gA = Ab + (long)(wave * 32 + rl) * lda + cb * 8;
    const bf16* gB = Bb + (long)(wave * 32 + rl) * ldb + cb * 8;
    char* lA = (char*)sA + wave * 32 * 128;
    char* lB = (char*)sB + wave * 32 * 128;

    f32x4 acc[4][4];
    const f32x4 zero = {0.f, 0.f, 0.f, 0.f};
#pragma unroll
    for (int i = 0; i < 4; i++)
#pragma unroll
        for (int j = 0; j < 4; j++) acc[i][j] = zero;

    for (int k0 = 0; k0 < Keff; k0 += 64) {
#pragma unroll
        for (int c = 0; c < 4; c++) {
            async_cp16(gA + (long)c * 8 * lda + k0, lA + c * 1024);
            async_cp16(gB + (long)c * 8 * ldb + k0, lB + c * 1024);
        }
        __syncthreads();   // compiler inserts vmcnt(0) drain before barrier
#pragma unroll
        for (int kk = 0; kk < 2; kk++) {
            bf16x8 af[4], bfr[4];
#pragma unroll
            for (int t = 0; t < 4; t++) {
                int row  = wm + t * 16 + r16;
                int slot = (kk * 4 + quad) ^ (row & 7);
                af[t] = *(const bf16x8*)((const char*)sA + row * 128 + slot * 16);
            }
#pragma unroll
            for (int t = 0; t < 4; t++) {
                int row  = wn + t * 16 + r16;
                int slot = (kk * 4 + quad) ^ (row & 7);
                bfr[t] = *(const bf16x8*)((const char*)sB + row * 128 + slot * 16);
            }
#pragma unroll
            for (int mt = 0; mt < 4; mt++)
#pragma unroll
                for (int nt = 0; nt < 4; nt++)
                    acc[mt][nt] = __builtin_amdgcn_mfma_f32_16x16x32_bf16(
                        af[mt], bfr[nt], acc[mt][nt], 0, 0, 0);
        }
        __syncthreads();
    }

    // epilogue: D[row=quad*4+reg][col=lane&15] per 16x16 tile
    const long Crow0 = (long)bm * 128, Ccol0 = (long)bn * 128;
    float* Cf = (float*)Cv;
    bf16*  Ch = (bf16*)Cv;
#pragma unroll
    for (int mt = 0; mt < 4; mt++) {
#pragma unroll
        for (int nt = 0; nt < 4; nt++) {
            long gcol = Ccol0 + wn + nt * 16 + r16;
            float badd = (flags & F_BIAS_N) ? bias[gcol] : 0.f;
#pragma unroll
            for (int rg = 0; rg < 4; rg++) {
                long grow = Crow0 + wm + mt * 16 + quad * 4 + rg;
                float v = acc[mt][nt][rg] * scale + badd;
                if (flags & F_BIAS_M) v += bias[grow];
                long off = (long)bz * strideC + grow * ldc + gcol;
                if (flags & F_OBF16) Ch[off] = __float2bfloat16(v);
                else                 Cf[off] = v;
            }
        }
    }
}

// Row-wise causal softmax, in place: fp32 scores row -> bf16 probs row (same bytes).
// One block per (batch,row); row length <= 2048 = 256 threads * 8.
__global__ __launch_bounds__(256) void softmax_causal(float* __restrict__ scores)
{
    const int rowg = blockIdx.x;                 // b*2048 + i
    float* srow = scores + (long)rowg * 2048;
    bf16*  prow = (bf16*)srow;
    const int i = rowg & 2047;
    const int n = i + 1;                          // valid entries
    const int width = ((i >> 7) + 1) << 7;        // pad to diagonal-block edge
    const int tid = threadIdx.x;

    float vals[8];
    float m = -1e30f;
#pragma unroll
    for (int t = 0; t < 8; t++) {
        int j = tid + t * 256;
        vals[t] = (j < n) ? srow[j] : -1e30f;
        m = fmaxf(m, vals[t]);
    }
    __shared__ float red[16];
#pragma unroll
    for (int o = 32; o > 0; o >>= 1) m = fmaxf(m, __shfl_xor(m, o));
    if ((tid & 63) == 0) red[tid >> 6] = m;
    __syncthreads();
    m = fmaxf(fmaxf(red[0], red[1]), fmaxf(red[2], red[3]));

    float s = 0.f;
#pragma unroll
    for (int t = 0; t < 8; t++) {
        float e = __expf(vals[t] - m);            // -1e30 -> 0
        vals[t] = e;
        s += e;
    }
#pragma unroll
    for (int o = 32; o > 0; o >>= 1) s += __shfl_xor(s, o);
    __syncthreads();
    if ((tid & 63) == 0) red[8 + (tid >> 6)] = s;
    __syncthreads();
    s = (red[8] + red[9]) + (red[10] + red[11]);
    const float inv = 1.f / s;

#pragma unroll
    for (int t = 0; t < 8; t++) {
        int j = tid + t * 256;
        if (j < width) prow[j] = __float2bfloat16(vals[t] * inv);
    }
}

__global__ __launch_bounds__(256) void cvt_bf16(const float* __restrict__ s,
                                                bf16* __restrict__ d, long n)
{
    long i = ((long)blockIdx.x * 256 + threadIdx.x) * 4;
    if (i + 3 < n) {
        float4 v = *(const float4*)(s + i);
        union { ushort4 u; bf16 h[4]; } o;
        o.h[0] = __float2bfloat16(v.x);
        o.h[1] = __float2bfloat16(v.y);
        o.h[2] = __float2bfloat16(v.z);
        o.h[3] = __float2bfloat16(v.w);
        *(ushort4*)(d + i) = o.u;
    }
}

extern "C" void kernel_launch(void* const* d_in, const int* in_sizes, int n_in,
                              void* d_out, int out_size, void* d_ws, size_t ws_size,
                              hipStream_t stream)
{
    (void)in_sizes; (void)n_in; (void)out_size; (void)ws_size;
    const float* x  = (const float*)d_in[0];
    const float* Wq = (const float*)d_in[1];
    const float* bq = (const float*)d_in[2];
    const float* Wk = (const float*)d_in[3];
    const float* bk = (const float*)d_in[4];
    const float* Wv = (const float*)d_in[5];
    const float* bv = (const float*)d_in[6];
    float* out = (float*)d_out;

    char* ws = (char*)d_ws;
    bf16* xb  = (bf16*)ws;  ws += (long)8192 * 1024 * 2;   // 16 MB
    bf16* Wqb = (bf16*)ws;  ws += (long)1024 * 1024 * 2;   //  2 MB
    bf16* Wkb = (bf16*)ws;  ws += (long)1024 * 1024 * 2;
    bf16* Wvb = (bf16*)ws;  ws += (long)1024 * 1024 * 2;
    bf16* Qb  = (bf16*)ws;  ws += (long)8192 * 1024 * 2;
    bf16* Kb  = (bf16*)ws;  ws += (long)8192 * 1024 * 2;
    bf16* Vt  = (bf16*)ws;  ws += (long)8192 * 1024 * 2;   // V^T [1024, 8192]
    float* Sc = (float*)ws;                                 // 64 MB scores / P

    cvt_bf16<<<8192, 256, 0, stream>>>(x,  xb,  8388608);
    cvt_bf16<<<1024, 256, 0, stream>>>(Wq, Wqb, 1048576);
    cvt_bf16<<<1024, 256, 0, stream>>>(Wk, Wkb, 1048576);
    cvt_bf16<<<1024, 256, 0, stream>>>(Wv, Wvb, 1048576);

    // Q = xb * Wq^T + bq   [8192,1024] bf16
    gemm_bt<<<dim3(8, 64, 1), 256, 0, stream>>>(
        xb, Wqb, Qb, 1024, 1024, 1024, 0, 0, 0, 1024, F_OBF16 | F_BIAS_N, bq, 1.f);
    // K = xb * Wk^T + bk
    gemm_bt<<<dim3(8, 64, 1), 256, 0, stream>>>(
        xb, Wkb, Kb, 1024, 1024, 1024, 0, 0, 0, 1024, F_OBF16 | F_BIAS_N, bk, 1.f);
    // V^T = Wv * xb^T + bv(per-row)   [1024,8192] bf16
    gemm_bt<<<dim3(64, 8, 1), 256, 0, stream>>>(
        Wvb, xb, Vt, 1024, 1024, 8192, 0, 0, 0, 1024, F_OBF16 | F_BIAS_M, bv, 1.f);
    // scores = Q*K^T / 32, fp32, lower-triangular blocks only, per batch
    gemm_bt<<<dim3(16, 16, 4), 256, 0, stream>>>(
        Qb, Kb, Sc, 1024, 1024, 2048,
        2048L * 1024, 2048L * 1024, 2048L * 2048, 1024, F_CSKIP, nullptr, 0.03125f);
    // softmax rows, in-place fp32 -> bf16 (P), zero-padded to diagonal block edge
    softmax_causal<<<8192, 256, 0, stream>>>(Sc);
    // out = P * V  (A = P bf16 lda=4096 over the fp32 score rows; B = V^T), causal K-limit
    gemm_bt<<<dim3(8, 16, 4), 256, 0, stream>>>(
        (const bf16*)Sc, Vt, out, 4096, 8192, 1024,
        2048L * 4096, 2048, 2048L * 1024, 2048, F_CK, nullptr, 1.f);
}

// Round 2
// 266.479 us; speedup vs baseline: 1.0532x; 1.0532x over previous
//
#include <hip/hip_runtime.h>
#include <hip/hip_bf16.h>
#include <stdint.h>

using bf16 = __hip_bfloat16;
typedef __bf16 bf16x8 __attribute__((ext_vector_type(8)));
typedef float  f32x4  __attribute__((ext_vector_type(4)));

#define AS1 __attribute__((address_space(1)))
#define AS3 __attribute__((address_space(3)))

__device__ __forceinline__ void async_cp16(const void* g, void* l) {
    __builtin_amdgcn_global_load_lds((const AS1 void*)g, (AS3 void*)l, 16, 0, 0);
}

enum { F_CSKIP = 1, F_CK = 2, F_OBF16 = 4 };

// ---------------------------------------------------------------------------
// Double-buffered GEMM: C[M,N] = scale * A[M,K] * B[N,K]^T. Both K-major bf16.
// 128x128 tile, BK=64, one barrier per K-iter, prefetch of iter k+1 overlaps
// compute of iter k. LDS = 64 KB -> 2 blocks/CU (matches grid/CU here).
// ---------------------------------------------------------------------------
__global__ __launch_bounds__(256, 2) void gemm_db(
    const bf16* __restrict__ A, const bf16* __restrict__ B, void* __restrict__ Cv,
    long lda, long ldb, long ldc,
    long strideA, long strideB, long strideC,
    int K, int flags, float scale)
{
    const int bm = blockIdx.y, bn = blockIdx.x, bz = blockIdx.z;
    if ((flags & F_CSKIP) && bn > bm) return;              // causal upper blocks
    const int Keff = (flags & F_CK) ? (bm + 1) * 128 : K;  // causal K-limit

    __shared__ bf16 sA[2][128 * 64];
    __shared__ bf16 sB[2][128 * 64];

    const int tid  = threadIdx.x;
    const int wave = tid >> 6, lane = tid & 63;
    const int wm = (wave >> 1) * 64, wn = (wave & 1) * 64;
    const int quad = lane >> 4, r16 = lane & 15;

    const bf16* Ab = A + (long)bz * strideA + (long)bm * 128 * lda;
    const bf16* Bb = B + (long)bz * strideB + (long)bn * 128 * ldb;

    // staging: wave stages 32 rows of A and B (4 chunks x 8 rows, 1 KB each).
    // LDS: row-major [128][64] bf16; 16B blocks XOR-swizzled (slot = c ^ (row&7)).
    const int rl = lane >> 3;
    const int cb = (lane & 7) ^ rl;
    const bf16* gA = Ab + (long)(wave * 32 + rl) * lda + cb * 8;
    const bf16* gB = Bb + (long)(wave * 32 + rl) * ldb + cb * 8;

    f32x4 acc[4][4];
    const f32x4 zero = {0.f, 0.f, 0.f, 0.f};
#pragma unroll
    for (int i = 0; i < 4; i++)
#pragma unroll
        for (int j = 0; j < 4; j++) acc[i][j] = zero;

    auto stage = [&](int buf, int k0) {
        char* lA = (char*)sA[buf] + wave * 32 * 128;
        char* lB = (char*)sB[buf] + wave * 32 * 128;
#pragma unroll
        for (int c = 0; c < 4; c++) {
            async_cp16(gA + (long)c * 8 * lda + k0, lA + c * 1024);
            async_cp16(gB + (long)c * 8 * ldb + k0, lB + c * 1024);
        }
    };

    const int nIter = Keff >> 6;
    stage(0, 0);
    for (int it = 0; it < nIter; ++it) {
        __syncthreads();   // vmcnt(0) drain: buf[it&1] ready; prev readers of buf[(it+1)&1] done
        if (it + 1 < nIter) stage((it + 1) & 1, (it + 1) << 6);
        const char* cA = (const char*)sA[it & 1];
        const char* cB = (const char*)sB[it & 1];
#pragma unroll
        for (int kk = 0; kk < 2; kk++) {
            bf16x8 af[4], bfr[4];
#pragma unroll
            for (int t = 0; t < 4; t++) {
                int row  = wm + t * 16 + r16;
                int slot = (kk * 4 + quad) ^ (row & 7);
                af[t] = *(const bf16x8*)(cA + row * 128 + slot * 16);
            }
#pragma unroll
            for (int t = 0; t < 4; t++) {
                int row  = wn + t * 16 + r16;
                int slot = (kk * 4 + quad) ^ (row & 7);
                bfr[t] = *(const bf16x8*)(cB + row * 128 + slot * 16);
            }
#pragma unroll
            for (int mt = 0; mt < 4; mt++)
#pragma unroll
                for (int nt = 0; nt < 4; nt++)
                    acc[mt][nt] = __builtin_amdgcn_mfma_f32_16x16x32_bf16(
                        af[mt], bfr[nt], acc[mt][nt], 0, 0, 0);
        }
    }

    const long Crow0 = (long)bm * 128, Ccol0 = (long)bn * 128;
    float* Cf = (float*)Cv;
    bf16*  Ch = (bf16*)Cv;
#pragma unroll
    for (int mt = 0; mt < 4; mt++) {
#pragma unroll
        for (int nt = 0; nt < 4; nt++) {
            long gcol = Ccol0 + wn + nt * 16 + r16;
#pragma unroll
            for (int rg = 0; rg < 4; rg++) {
                long grow = Crow0 + wm + mt * 16 + quad * 4 + rg;
                float v = acc[mt][nt][rg] * scale;
                long off = (long)bz * strideC + grow * ldc + gcol;
                if (flags & F_OBF16) Ch[off] = __float2bfloat16(v);
                else                 Cf[off] = v;
            }
        }
    }
}

// ---------------------------------------------------------------------------
// Fused QKV projection: one dispatch, grid (24, 64). bn 0-7 -> Q, 8-15 -> K,
// 16-23 -> V (written transposed into Vt[1024][8192]). Single-buffer 32 KB LDS
// -> 5 blocks/CU co-resident out of a 1536-block grid.
// ---------------------------------------------------------------------------
__global__ __launch_bounds__(256, 2) void gemm_qkv(
    const bf16* __restrict__ xb,
    const bf16* __restrict__ Wqb, const bf16* __restrict__ Wkb, const bf16* __restrict__ Wvb,
    const float* __restrict__ bq, const float* __restrict__ bk, const float* __restrict__ bv,
    bf16* __restrict__ Qb, bf16* __restrict__ Kb, bf16* __restrict__ Vt)
{
    const int bn = blockIdx.x, bm = blockIdx.y;
    const int seg = bn >> 3, bn_loc = bn & 7;
    const bf16*  W    = seg == 0 ? Wqb : (seg == 1 ? Wkb : Wvb);
    const float* bias = seg == 0 ? bq  : (seg == 1 ? bk  : bv);

    __shared__ bf16 sA[128 * 64];
    __shared__ bf16 sB[128 * 64];

    const int tid  = threadIdx.x;
    const int wave = tid >> 6, lane = tid & 63;
    const int wm = (wave >> 1) * 64, wn = (wave & 1) * 64;
    const int quad = lane >> 4, r16 = lane & 15;

    const bf16* Ab = xb + (long)bm * 128 * 1024;
    const bf16* Bb = W  + (long)bn_loc * 128 * 1024;

    const int rl = lane >> 3;
    const int cb = (lane & 7) ^ rl;
    const bf16* gA = Ab + (long)(wave * 32 + rl) * 1024 + cb * 8;
    const bf16* gB = Bb + (long)(wave * 32 + rl) * 1024 + cb * 8;
    char* lA = (char*)sA + wave * 32 * 128;
    char* lB = (char*)sB + wave * 32 * 128;

    f32x4 acc[4][4];
    const f32x4 zero = {0.f, 0.f, 0.f, 0.f};
#pragma unroll
    for (int i = 0; i < 4; i++)
#pragma unroll
        for (int j = 0; j < 4; j++) acc[i][j] = zero;

    for (int k0 = 0; k0 < 1024; k0 += 64) {
#pragma unroll
        for (int c = 0; c < 4; c++) {
            async_cp16(gA + (long)c * 8 * 1024 + k0, lA + c * 1024);
            async_cp16(gB + (long)c * 8 * 1024 + k0, lB + c * 1024);
        }
        __syncthreads();
#pragma unroll
        for (int kk = 0; kk < 2; kk++) {
            bf16x8 af[4], bfr[4];
#pragma unroll
            for (int t = 0; t < 4; t++) {
                int row  = wm + t * 16 + r16;
                int slot = (kk * 4 + quad) ^ (row & 7);
                af[t] = *(const bf16x8*)((const char*)sA + row * 128 + slot * 16);
            }
#pragma unroll
            for (int t = 0; t < 4; t++) {
                int row  = wn + t * 16 + r16;
                int slot = (kk * 4 + quad) ^ (row & 7);
                bfr[t] = *(const bf16x8*)((const char*)sB + row * 128 + slot * 16);
            }
#pragma unroll
            for (int mt = 0; mt < 4; mt++)
#pragma unroll
                for (int nt = 0; nt < 4; nt++)
                    acc[mt][nt] = __builtin_amdgcn_mfma_f32_16x16x32_bf16(
                        af[mt], bfr[nt], acc[mt][nt], 0, 0, 0);
        }
        __syncthreads();
    }

    bf16* O = seg == 0 ? Qb : Kb;   // seg<2 path
#pragma unroll
    for (int mt = 0; mt < 4; mt++) {
#pragma unroll
        for (int nt = 0; nt < 4; nt++) {
            int col = bn_loc * 128 + wn + nt * 16 + r16;        // 0..1023
            float badd = bias[col];
#pragma unroll
            for (int rg = 0; rg < 4; rg++) {
                long token = (long)bm * 128 + wm + mt * 16 + quad * 4 + rg;
                bf16 v = __float2bfloat16(acc[mt][nt][rg] + badd);
                if (seg < 2) O[token * 1024 + col] = v;
                else         Vt[(long)col * 8192 + token] = v;
            }
        }
    }
}

// Row-wise causal softmax, in place: fp32 score row -> bf16 prob row.
__global__ __launch_bounds__(256) void softmax_causal(float* __restrict__ scores)
{
    const int rowg = blockIdx.x;                 // b*2048 + i
    float* srow = scores + (long)rowg * 2048;
    bf16*  prow = (bf16*)srow;
    const int i = rowg & 2047;
    const int n = i + 1;
    const int width = ((i >> 7) + 1) << 7;       // pad to diagonal-block edge
    const int tid = threadIdx.x;

    float vals[8];
    float m = -1e30f;
#pragma unroll
    for (int t = 0; t < 8; t++) {
        int j = tid + t * 256;
        vals[t] = (j < n) ? srow[j] : -1e30f;
        m = fmaxf(m, vals[t]);
    }
    __shared__ float red[16];
#pragma unroll
    for (int o = 32; o > 0; o >>= 1) m = fmaxf(m, __shfl_xor(m, o));
    if ((tid & 63) == 0) red[tid >> 6] = m;
    __syncthreads();
    m = fmaxf(fmaxf(red[0], red[1]), fmaxf(red[2], red[3]));

    float s = 0.f;
#pragma unroll
    for (int t = 0; t < 8; t++) {
        float e = __expf(vals[t] - m);
        vals[t] = e;
        s += e;
    }
#pragma unroll
    for (int o = 32; o > 0; o >>= 1) s += __shfl_xor(s, o);
    __syncthreads();
    if ((tid & 63) == 0) red[8 + (tid >> 6)] = s;
    __syncthreads();
    s = (red[8] + red[9]) + (red[10] + red[11]);
    const float inv = 1.f / s;

#pragma unroll
    for (int t = 0; t < 8; t++) {
        int j = tid + t * 256;
        if (j < width) prow[j] = __float2bfloat16(vals[t] * inv);
    }
}

__global__ __launch_bounds__(256) void cvt_bf16(const float* __restrict__ s,
                                                bf16* __restrict__ d, long n)
{
    long i = ((long)blockIdx.x * 256 + threadIdx.x) * 4;
    if (i + 3 < n) {
        float4 v = *(const float4*)(s + i);
        union { ushort4 u; bf16 h[4]; } o;
        o.h[0] = __float2bfloat16(v.x);
        o.h[1] = __float2bfloat16(v.y);
        o.h[2] = __float2bfloat16(v.z);
        o.h[3] = __float2bfloat16(v.w);
        *(ushort4*)(d + i) = o.u;
    }
}

// Convert the three 1024x1024 weight matrices in one dispatch (grid.y selects).
__global__ __launch_bounds__(256) void cvt_w3(
    const float* __restrict__ Wq, const float* __restrict__ Wk, const float* __restrict__ Wv,
    bf16* __restrict__ dq, bf16* __restrict__ dk, bf16* __restrict__ dv)
{
    const int w = blockIdx.y;
    const float* s = w == 0 ? Wq : (w == 1 ? Wk : Wv);
    bf16* d = w == 0 ? dq : (w == 1 ? dk : dv);
    long i = ((long)blockIdx.x * 256 + threadIdx.x) * 4;
    float4 v = *(const float4*)(s + i);
    union { ushort4 u; bf16 h[4]; } o;
    o.h[0] = __float2bfloat16(v.x);
    o.h[1] = __float2bfloat16(v.y);
    o.h[2] = __float2bfloat16(v.z);
    o.h[3] = __float2bfloat16(v.w);
    *(ushort4*)(d + i) = o.u;
}

extern "C" void kernel_launch(void* const* d_in, const int* in_sizes, int n_in,
                              void* d_out, int out_size, void* d_ws, size_t ws_size,
                              hipStream_t stream)
{
    (void)in_sizes; (void)n_in; (void)out_size; (void)ws_size;
    const float* x  = (const float*)d_in[0];
    const float* Wq = (const float*)d_in[1];
    const float* bq = (const float*)d_in[2];
    const float* Wk = (const float*)d_in[3];
    const float* bk = (const float*)d_in[4];
    const float* Wv = (const float*)d_in[5];
    const float* bv = (const float*)d_in[6];
    float* out = (float*)d_out;

    char* ws = (char*)d_ws;
    bf16* xb  = (bf16*)ws;  ws += (long)8192 * 1024 * 2;   // 16 MB
    bf16* Wqb = (bf16*)ws;  ws += (long)1024 * 1024 * 2;   //  2 MB
    bf16* Wkb = (bf16*)ws;  ws += (long)1024 * 1024 * 2;
    bf16* Wvb = (bf16*)ws;  ws += (long)1024 * 1024 * 2;
    bf16* Qb  = (bf16*)ws;  ws += (long)8192 * 1024 * 2;
    bf16* Kb  = (bf16*)ws;  ws += (long)8192 * 1024 * 2;
    bf16* Vt  = (bf16*)ws;  ws += (long)8192 * 1024 * 2;   // V^T [1024][8192]
    float* Sc = (float*)ws;                                 // 64 MB scores / P

    cvt_bf16<<<8192, 256, 0, stream>>>(x, xb, 8388608);
    cvt_w3<<<dim3(1024, 3), 256, 0, stream>>>(Wq, Wk, Wv, Wqb, Wkb, Wvb);

    // Q, K row-major [8192,1024]; V^T [1024][8192] -- one dispatch, 1536 blocks
    gemm_qkv<<<dim3(24, 64), 256, 0, stream>>>(
        xb, Wqb, Wkb, Wvb, bq, bk, bv, Qb, Kb, Vt);

    // scores = Q*K^T / 32, fp32, lower-triangular blocks only, per batch
    gemm_db<<<dim3(16, 16, 4), 256, 0, stream>>>(
        Qb, Kb, Sc, 1024, 1024, 2048,
        2048L * 1024, 2048L * 1024, 2048L * 2048, 1024, F_CSKIP, 0.03125f);

    softmax_causal<<<8192, 256, 0, stream>>>(Sc);

    // out = P * V  (A = P bf16 lda=4096 over fp32 rows; B = V^T), causal K-limit
    gemm_db<<<dim3(8, 16, 4), 256, 0, stream>>>(
        (const bf16*)Sc, Vt, out, 4096, 8192, 1024,
        2048L * 4096, 2048, 2048L * 1024, 2048, F_CK, 1.f);
}